// Round 5
// baseline (1241.735 us; speedup 1.0000x reference)
//
#include <hip/hip_runtime.h>

#define VOCAB 30000
#define MPAD  30080   // 235 * 128
#define G_MT  120     // 256-row m-tiles padded to multiple of 8 (XCD count)

typedef __attribute__((ext_vector_type(8))) short bf16x8;
typedef __attribute__((ext_vector_type(4))) float f32x4;

__device__ __forceinline__ unsigned short f2bf(float f) {
    unsigned int u = __builtin_bit_cast(unsigned int, f);
    u += 0x7fffu + ((u >> 16) & 1u);          // round-to-nearest-even
    return (unsigned short)(u >> 16);
}
__device__ __forceinline__ float bf2f(unsigned int h) {
    unsigned int u = h << 16;
    return __builtin_bit_cast(float, u);
}

__device__ __forceinline__ void async16(const void* g, void* l) {
    __builtin_amdgcn_global_load_lds(
        (__attribute__((address_space(1))) void*)g,
        (__attribute__((address_space(3))) void*)l, 16, 0, 0);
}

// ---------------- compaction ----------------
// flags relies on the harness's 0xAA ws poison: "marked" == exactly 1.
__global__ void k_mark(const int* __restrict__ ingrs, const int* __restrict__ lengths,
                       int* __restrict__ flags, int* __restrict__ cnt)
{
    const int i = blockIdx.x * 256 + threadIdx.x;
    if (i == 0) *cnt = 0;
    if (i >= 4096 * 20) return;
    const int b = i / 20;
    const int l = i - b * 20;
    if (l < lengths[b]) flags[ingrs[i]] = 1;
}

__global__ void k_assign(const int* __restrict__ flags, int* __restrict__ remap,
                         int* __restrict__ cnt)
{
    const int i = blockIdx.x * 256 + threadIdx.x;
    if (i < VOCAB && flags[i] == 1) remap[i] = atomicAdd(cnt, 1);
}

// ---------------- transpose helper ----------------
__device__ __forceinline__ void transpose_body(
    const float* __restrict__ in, unsigned short* __restrict__ out,
    int K, int Nin, int n0, int k0, int tid, float (*t)[65])
{
#pragma unroll
    for (int p = 0; p < 16; ++p) {
        const int lin = p * 256 + tid;
        const int kk = lin >> 6, nn = lin & 63;
        const int n = n0 + nn;
        t[kk][nn] = (n < Nin) ? in[(size_t)(k0 + kk) * Nin + n] : 0.f;
    }
    __syncthreads();
#pragma unroll
    for (int p = 0; p < 16; ++p) {
        const int lin = p * 256 + tid;
        const int nn = lin >> 6, kk = lin & 63;
        out[(size_t)(n0 + nn) * K + k0 + kk] = f2bf(t[kk][nn]);
    }
}

// ---------------- 256x256 8-wave GEMM, BK=32 dbuf, 64 KiB LDS -------------
// 2 blocks/CU (the round-4 128 KiB version capped at 1 block/CU = 25% occ;
// cross-block overlap is the mechanism that fills barrier/LDS windows, m114).
// Per K-tile: 2 phases of {ds_read; [ph0: stage all 4 units of t+1];
// s_barrier; lgkmcnt(0)+sched_barrier; setprio(1); 16 MFMA; setprio(0);
// [ph1: vmcnt(0) for loads issued 1.5 phases earlier]; s_barrier}.
// LDS (shorts): A[buf][256][32] at buf*8192; B at 16384 + buf*8192.
// Swizzle: 64-B rows, 4 chunks; phys_chunk = q ^ ((row>>1)&3) — balanced
// 2-way across the 8 bank-slots (free per m136).
#define MF(a, b, c) __builtin_amdgcn_mfma_f32_16x16x32_bf16(a, b, c, 0, 0, 0)

#define G_BAR()  __builtin_amdgcn_s_barrier()
#define G_LGKM() do { asm volatile("s_waitcnt lgkmcnt(0)" ::: "memory");       \
                      __builtin_amdgcn_sched_barrier(0); } while (0)

__device__ __forceinline__ void gemm256_body(
    unsigned short* lds,
    const unsigned short* __restrict__ A, const unsigned short* __restrict__ BT,
    const float* __restrict__ bias, int bias_n, unsigned short* __restrict__ C,
    int K, int NK, int N, int relu, int mc, int id, int nt_shift)
{
    const int w  = id >> 3;
    const int n_tile = w & ((1 << nt_shift) - 1);
    const int m_tile = (id & 7) + ((w >> nt_shift) << 3);  // XCD-banded m
    const int m0 = m_tile * 256;
    if (m0 >= mc) return;
    const int n0 = n_tile * 256;

    const int tid  = threadIdx.x;
    const int lane = tid & 63;
    const int w0   = tid >> 6;                // wave 0..7
    const int wr   = w0 >> 2;                 // 0..1  (128-row half of M)
    const int wc   = w0 & 3;                  // 0..3  (64-col strip of N)
    const int q    = lane >> 4;
    const int ml   = lane & 15;
    const int rswz = (ml >> 1) & 3;

    f32x4 acc[8][4];
    const f32x4 zero = {0.f, 0.f, 0.f, 0.f};
#pragma unroll
    for (int i = 0; i < 8; ++i)
#pragma unroll
        for (int j = 0; j < 4; ++j) acc[i][j] = zero;

    // staging: wave w0 covers rows [w0*32, w0*32+32) of A and of BT; one
    // async16 call = 16 rows x 64 B.  Global source pre-swizzled:
    // src chunk = (lane&3) ^ ((row>>1)&3) with row = w0*32 + h*16 + (lane>>2)
    // -> swz reduces to (lane>>3)&3.
    const int schunk = (lane & 3) ^ ((lane >> 3) & 3);
    const unsigned short* gA = A  + (size_t)(m0 + w0 * 32 + (lane >> 2)) * K + schunk * 8;
    const unsigned short* gB = BT + (size_t)(n0 + w0 * 32 + (lane >> 2)) * K + schunk * 8;
    const int sdst = (w0 * 32) * 32 + lane * 8;   // shorts; lane*16B per HW rule

#define G_U(AB, H, B_, T) do {                                                 \
        const unsigned short* _s = ((AB) ? gB : gA)                            \
            + (size_t)((H) * 16) * K + (size_t)(T) * 32;                       \
        unsigned short* _d = &lds[(AB) * 16384 + (B_) * 8192 + (H) * 512 + sdst]; \
        async16(_s, _d);                                                       \
    } while (0)

#define LDA(I) (*(const bf16x8*)&lds[cb + ((wr * 128 + (I) * 16 + ml) * 32) + ((q ^ rswz) * 8)])
#define LDB(J) (*(const bf16x8*)&lds[16384 + cb + ((wc * 64 + (J) * 16 + ml) * 32) + ((q ^ rswz) * 8)])

    // prologue: stage tile 0 into buf0
    G_U(0, 0, 0, 0); G_U(0, 1, 0, 0); G_U(1, 0, 0, 0); G_U(1, 1, 0, 0);
    asm volatile("s_waitcnt vmcnt(0)" ::: "memory");
    G_BAR();

    for (int t = 0; t < NK; ++t) {
        const int cb  = (t & 1) * 8192;
        const int nxt = (t & 1) ^ 1;
        bf16x8 afr[4], bfr[4];

        // ---- ph0: acc rows 0-3; issue all of t+1's staging (wait is 1.5
        // phases later -> issue-early / wait-late) ----
#pragma unroll
        for (int j = 0; j < 4; ++j) bfr[j] = LDB(j);
#pragma unroll
        for (int i = 0; i < 4; ++i) afr[i] = LDA(i);
        if (t + 1 < NK) {
            G_U(0, 0, nxt, t + 1); G_U(0, 1, nxt, t + 1);
            G_U(1, 0, nxt, t + 1); G_U(1, 1, nxt, t + 1);
        }
        G_BAR(); G_LGKM();
        __builtin_amdgcn_s_setprio(1);
#pragma unroll
        for (int i = 0; i < 4; ++i)
#pragma unroll
            for (int j = 0; j < 4; ++j)
                acc[i][j] = MF(afr[i], bfr[j], acc[i][j]);
        __builtin_amdgcn_s_setprio(0);
        G_BAR();

        // ---- ph1: acc rows 4-7; wait t+1's loads at the end ----
#pragma unroll
        for (int i = 0; i < 4; ++i) afr[i] = LDA(4 + i);
        G_BAR(); G_LGKM();
        __builtin_amdgcn_s_setprio(1);
#pragma unroll
        for (int i = 0; i < 4; ++i)
#pragma unroll
            for (int j = 0; j < 4; ++j)
                acc[4 + i][j] = MF(afr[i], bfr[j], acc[4 + i][j]);
        __builtin_amdgcn_s_setprio(0);
        asm volatile("s_waitcnt vmcnt(0)" ::: "memory");
        G_BAR();
    }

#undef G_U
#undef LDA
#undef LDB

    // ---- epilogue: 4 passes of 64 rows via LDS (stride 272 shorts) ----
    float bv[4];
#pragma unroll
    for (int j = 0; j < 4; ++j) {
        const int col = n0 + wc * 64 + j * 16 + ml;
        bv[j] = (col < bias_n) ? bias[col] : 0.f;
    }
    for (int p2 = 0; p2 < 4; ++p2) {
        const int h = p2 >> 1;
        if (wr == h) {
#pragma unroll
            for (int ii = 0; ii < 4; ++ii) {
                const int I = ((p2 & 1) ? 4 : 0) + ii;
#pragma unroll
                for (int j = 0; j < 4; ++j)
#pragma unroll
                    for (int r = 0; r < 4; ++r) {
                        float v = acc[I][j][r] + bv[j];
                        if (relu) v = fmaxf(v, 0.f);
                        lds[(ii * 16 + q * 4 + r) * 272 + wc * 64 + j * 16 + ml] = f2bf(v);
                    }
            }
        }
        __syncthreads();
#pragma unroll
        for (int p = 0; p < 4; ++p) {
            const int row  = p * 16 + (tid >> 5);
            const int c8   = (tid & 31) * 8;
            const int grow = m0 + h * 128 + (p2 & 1) * 64 + row;
            if (grow < MPAD) {
                *(uint4*)&C[(size_t)grow * N + n0 + c8] =
                    *(const uint4*)&lds[row * 272 + c8];
            }
        }
        __syncthreads();
    }
}

// ---------------- k_prep: A1 gather-activate | W2T | W3T | slots ----------
__global__ __launch_bounds__(256)
void k_prep(const float* __restrict__ W1, const float* __restrict__ b1,
            const int* __restrict__ flags, const int* __restrict__ remap,
            unsigned short* __restrict__ A1,
            const float* __restrict__ W2, unsigned short* __restrict__ W2T,
            const float* __restrict__ W3, unsigned short* __restrict__ W3T,
            const int* __restrict__ ingrs, const int* __restrict__ lengths,
            int* __restrict__ slots)
{
    __shared__ float t[64][65];
    const int bid = blockIdx.x;
    const int tid = threadIdx.x;

    if (bid < 15000) {                       // 2 vocab rows per block
        const int id = bid * 2 + (tid >> 7);
        if (flags[id] != 1) return;
        const int row = remap[id];
        const int k4  = (tid & 127) * 4;
        const float4 w  = *(const float4*)(W1 + (size_t)id * 512 + k4);
        const float4 bb = *(const float4*)(b1 + k4);
        unsigned short o[4];
        o[0] = f2bf(fmaxf(w.x + bb.x, 0.f));
        o[1] = f2bf(fmaxf(w.y + bb.y, 0.f));
        o[2] = f2bf(fmaxf(w.z + bb.z, 0.f));
        o[3] = f2bf(fmaxf(w.w + bb.w, 0.f));
        *(uint2*)(A1 + (size_t)row * 512 + k4) = *(const uint2*)o;
    } else if (bid < 15128) {                // W2 [512x1024] -> W2T [1024x512]
        const int local = bid - 15000;
        transpose_body(W2, W2T, 512, 1024, (local & 15) * 64, (local >> 4) * 64, tid, t);
    } else if (bid < 15640) {                // W3 [1024x2047] -> W3T [2048x1024]
        const int local = bid - 15128;
        transpose_body(W3, W3T, 1024, 2047, (local & 31) * 64, (local >> 5) * 64, tid, t);
    } else {                                 // slots[b,l] = remap[ingrs[b,l]]
        const int i = (bid - 15640) * 256 + tid;
        if (i < 4096 * 20) {
            const int b = i / 20;
            const int l = i - b * 20;
            if (l < lengths[b]) slots[i] = remap[ingrs[i]];
        }
    }
}

// ---------------- GEMM kernels (unified body) ----------------
__global__ __launch_bounds__(512, 4)
void k_gemm1(const unsigned short* __restrict__ A1, const unsigned short* __restrict__ W2T,
             const float* __restrict__ b2, unsigned short* __restrict__ H2,
             const int* __restrict__ cnt)
{
    __shared__ __align__(16) unsigned short lds[32768];
    const int mc = (*cnt + 255) & ~255;
    gemm256_body(lds, A1, W2T, b2, 1024, H2, 512, 16, 1024, 1, mc, blockIdx.x, 2);
}

__global__ __launch_bounds__(512, 4)
void k_gemm2(const unsigned short* __restrict__ H2, const unsigned short* __restrict__ W3T,
             const float* __restrict__ b3, unsigned short* __restrict__ Table,
             const int* __restrict__ cnt)
{
    __shared__ __align__(16) unsigned short lds[32768];
    const int mc = (*cnt + 255) & ~255;
    gemm256_body(lds, H2, W3T, b3, 2047, Table, 1024, 32, 2048, 0, mc, blockIdx.x, 3);
}

// ---------------- k_gather: one wave per batch row, 2-deep prefetch -------
__global__ __launch_bounds__(64)
void k_gather(const int* __restrict__ lengths, const int* __restrict__ slots,
              const unsigned short* __restrict__ Table, float* __restrict__ out)
{
    const int b    = blockIdx.x;
    const int lane = threadIdx.x;

    float acc[32];
#pragma unroll
    for (int j = 0; j < 32; ++j) acc[j] = 0.f;

    const int len = lengths[b];
    if (len > 0) {
        uint4 u0[4], u1[4];
        {
            const uint4* rp = (const uint4*)(Table + (size_t)slots[b * 20] * 2048);
#pragma unroll
            for (int c = 0; c < 4; ++c) u0[c] = rp[c * 64 + lane];
        }
        if (len > 1) {
            const uint4* rp = (const uint4*)(Table + (size_t)slots[b * 20 + 1] * 2048);
#pragma unroll
            for (int c = 0; c < 4; ++c) u1[c] = rp[c * 64 + lane];
        }
        for (int l = 0; l < len; ++l) {
            uint4 cu[4];
#pragma unroll
            for (int c = 0; c < 4; ++c) { cu[c] = u0[c]; u0[c] = u1[c]; }
            if (l + 2 < len) {                       // 2-deep prefetch
                const uint4* rp = (const uint4*)(Table + (size_t)slots[b * 20 + l + 2] * 2048);
#pragma unroll
                for (int c = 0; c < 4; ++c) u1[c] = rp[c * 64 + lane];
            }
            float v[32];
#pragma unroll
            for (int c = 0; c < 4; ++c) {
                v[c*8+0] = bf2f(cu[c].x & 0xffffu); v[c*8+1] = bf2f(cu[c].x >> 16);
                v[c*8+2] = bf2f(cu[c].y & 0xffffu); v[c*8+3] = bf2f(cu[c].y >> 16);
                v[c*8+4] = bf2f(cu[c].z & 0xffffu); v[c*8+5] = bf2f(cu[c].z >> 16);
                v[c*8+6] = bf2f(cu[c].w & 0xffffu); v[c*8+7] = bf2f(cu[c].w >> 16);
            }
            float s = 0.f;
#pragma unroll
            for (int j = 0; j < 32; ++j) s += v[j] * v[j];
#pragma unroll
            for (int off = 1; off < 64; off <<= 1) s += __shfl_xor(s, off, 64);
            const float invn = 1.0f / fmaxf(sqrtf(s), 1e-12f);
#pragma unroll
            for (int j = 0; j < 32; ++j) acc[j] += v[j] * invn;
        }
    }

    const size_t base = (size_t)b * 2047;
#pragma unroll
    for (int c = 0; c < 4; ++c) {
        const int col = (c * 64 + lane) * 8;
        if (c < 3 || lane != 63) {               // full 8 floats in-range
            *(float4*)&out[base + col]     = *(const float4*)&acc[c * 8];
            *(float4*)&out[base + col + 4] = *(const float4*)&acc[c * 8 + 4];
        } else {
#pragma unroll
            for (int j = 0; j < 7; ++j) out[base + col + j] = acc[c * 8 + j];
        }
    }
}

// ---------------- launch ----------------

extern "C" void kernel_launch(void* const* d_in, const int* in_sizes, int n_in,
                              void* d_out, int out_size, void* d_ws, size_t ws_size,
                              hipStream_t stream)
{
    const int*   ingrs   = (const int*)d_in[0];
    const int*   lengths = (const int*)d_in[1];
    const float* W1 = (const float*)d_in[2];
    const float* b1 = (const float*)d_in[3];
    const float* W2 = (const float*)d_in[4];
    const float* b2 = (const float*)d_in[5];
    const float* W3 = (const float*)d_in[6];
    const float* b3 = (const float*)d_in[7];
    float* out = (float*)d_out;

    char* ws = (char*)d_ws;
    unsigned short* A1    = (unsigned short*)(ws);
    unsigned short* H2    = (unsigned short*)(ws + 30801920);
    unsigned short* Table = (unsigned short*)(ws + 92405760);
    unsigned short* W2T   = (unsigned short*)(ws + 215613440);
    unsigned short* W3T   = (unsigned short*)(ws + 216662016);
    int*            flags = (int*)(ws + 220856320);
    int*            remap = (int*)(ws + 220976320);
    int*            cnt   = (int*)(ws + 221096320);
    int*            slots = (int*)(ws + 221216448);

    k_mark  <<<(4096 * 20 + 255) / 256, 256, 0, stream>>>(ingrs, lengths, flags, cnt);
    k_assign<<<(VOCAB + 255) / 256, 256, 0, stream>>>(flags, remap, cnt);
    // a1c (15000) | W2T (128) | W3T (512) | slots (320)
    k_prep<<<15960, 256, 0, stream>>>(W1, b1, flags, remap, A1, W2, W2T,
                                      W3, W3T, ingrs, lengths, slots);
    // GEMM1 (256^2 BK=32, 2 blocks/CU): H2 = relu(A1 @ W2 + b2)
    k_gemm1<<<G_MT * 4, 512, 0, stream>>>(A1, W2T, b2, H2, cnt);
    // GEMM2 (256^2 BK=32, 2 blocks/CU): Table = H2 @ W3 + b3
    k_gemm2<<<G_MT * 8, 512, 0, stream>>>(H2, W3T, b3, Table, cnt);

    k_gather<<<4096, 64, 0, stream>>>(lengths, slots, Table, out);
}

// Round 6
// 309.462 us; speedup vs baseline: 4.0126x; 4.0126x over previous
//
#include <hip/hip_runtime.h>

#define VOCAB 30000
#define MPAD  30080   // 235 * 128
#define G_MT  120     // 256-row m-tiles padded to multiple of 8 (XCD count)

typedef __attribute__((ext_vector_type(8))) short bf16x8;
typedef __attribute__((ext_vector_type(4))) float f32x4;

__device__ __forceinline__ unsigned short f2bf(float f) {
    unsigned int u = __builtin_bit_cast(unsigned int, f);
    u += 0x7fffu + ((u >> 16) & 1u);          // round-to-nearest-even
    return (unsigned short)(u >> 16);
}
__device__ __forceinline__ float bf2f(unsigned int h) {
    unsigned int u = h << 16;
    return __builtin_bit_cast(float, u);
}

__device__ __forceinline__ void async16(const void* g, void* l) {
    __builtin_amdgcn_global_load_lds(
        (__attribute__((address_space(1))) void*)g,
        (__attribute__((address_space(3))) void*)l, 16, 0, 0);
}

// ---------------- compaction ----------------
// flags relies on the harness's 0xAA ws poison: "marked" == exactly 1.
__global__ void k_mark(const int* __restrict__ ingrs, const int* __restrict__ lengths,
                       int* __restrict__ flags, int* __restrict__ cnt)
{
    const int i = blockIdx.x * 256 + threadIdx.x;
    if (i == 0) *cnt = 0;
    if (i >= 4096 * 20) return;
    const int b = i / 20;
    const int l = i - b * 20;
    if (l < lengths[b]) flags[ingrs[i]] = 1;
}

__global__ void k_assign(const int* __restrict__ flags, int* __restrict__ remap,
                         int* __restrict__ cnt)
{
    const int i = blockIdx.x * 256 + threadIdx.x;
    if (i < VOCAB && flags[i] == 1) remap[i] = atomicAdd(cnt, 1);
}

// ---------------- transpose helper ----------------
__device__ __forceinline__ void transpose_body(
    const float* __restrict__ in, unsigned short* __restrict__ out,
    int K, int Nin, int n0, int k0, int tid, float (*t)[65])
{
#pragma unroll
    for (int p = 0; p < 16; ++p) {
        const int lin = p * 256 + tid;
        const int kk = lin >> 6, nn = lin & 63;
        const int n = n0 + nn;
        t[kk][nn] = (n < Nin) ? in[(size_t)(k0 + kk) * Nin + n] : 0.f;
    }
    __syncthreads();
#pragma unroll
    for (int p = 0; p < 16; ++p) {
        const int lin = p * 256 + tid;
        const int nn = lin >> 6, kk = lin & 63;
        out[(size_t)(n0 + nn) * K + k0 + kk] = f2bf(t[kk][nn]);
    }
}

// ---------------- unified 256x256 8-wave 4-phase GEMM body ----------------
// Round-4 verified configuration: BK=64 dbuf, 128 KiB LDS, 1 block/CU
// (acc[8][4]=128 VGPR forbids 2 blocks/CU -- round-5 spill disaster).
// Per K-tile: 4 phases of {ds_read subtile; stage one half-tile unit
// (2 x global_load_lds); s_barrier; lgkmcnt(0)+sched_barrier; setprio(1);
// 16 MFMA; setprio(0); s_barrier}.  Stage units recycle LDS half-regions
// whose last reader finished >=1 phase earlier; per-tile wait is vmcnt(4)
// (never 0 until the drain).  Every staged unit gets >=3 phases of flight.
#define MF(a, b, c) __builtin_amdgcn_mfma_f32_16x16x32_bf16(a, b, c, 0, 0, 0)

#define G_U(AB, H, B_, T) do {                                                 \
        const unsigned short* _s = ((AB) ? gB : gA)                            \
            + (size_t)((H) * 128) * K + (size_t)(T) * 64;                      \
        unsigned short* _d = &lds[(AB) * 32768 + (B_) * 16384                  \
            + ((H) * 128) * 64 + dst0];                                        \
        async16(_s, _d);                                                       \
        async16(_s + (size_t)8 * K, _d + 8 * 64);                              \
    } while (0)

#define LDA(I, S) (*(const bf16x8*)&lds[cb + ((wr * 128 + (I) * 16 + ml) * 64) + ((((S) * 4 + q) ^ m7) * 8)])
#define LDB(J, S) (*(const bf16x8*)&lds[32768 + cb + ((wc * 64 + (J) * 16 + ml) * 64) + ((((S) * 4 + q) ^ m7) * 8)])

#define G_MFMA16(AI0, BF)                                                      \
        _Pragma("unroll")                                                      \
        for (int i = 0; i < 4; ++i)                                            \
        _Pragma("unroll")                                                      \
        for (int j = 0; j < 4; ++j)                                            \
            acc[(AI0) + i][j] = MF(afr[i], BF[j], acc[(AI0) + i][j]);

#define G_BAR()  __builtin_amdgcn_s_barrier()
#define G_LGKM() do { asm volatile("s_waitcnt lgkmcnt(0)" ::: "memory");       \
                      __builtin_amdgcn_sched_barrier(0); } while (0)

__device__ __forceinline__ void gemm256_body(
    unsigned short* lds,
    const unsigned short* __restrict__ A, const unsigned short* __restrict__ BT,
    const float* __restrict__ bias, int bias_n, unsigned short* __restrict__ C,
    int K, int NK, int N, int relu, int mc, int id, int nt_shift)
{
    const int w  = id >> 3;
    const int n_tile = w & ((1 << nt_shift) - 1);
    const int m_tile = (id & 7) + ((w >> nt_shift) << 3);  // XCD-banded m
    const int m0 = m_tile * 256;
    if (m0 >= mc) return;
    const int n0 = n_tile * 256;

    const int tid  = threadIdx.x;
    const int lane = tid & 63;
    const int w0   = tid >> 6;                // wave 0..7
    const int wr   = w0 >> 2;                 // 0..1  (128-row half)
    const int wc   = w0 & 3;                  // 0..3  (64-col strip)
    const int q    = lane >> 4;
    const int ml   = lane & 15;
    const int m7   = ml & 7;

    f32x4 acc[8][4];
    const f32x4 zero = {0.f, 0.f, 0.f, 0.f};
#pragma unroll
    for (int i = 0; i < 8; ++i)
#pragma unroll
        for (int j = 0; j < 4; ++j) acc[i][j] = zero;

    // staging: each wave covers rows [w0*16, w0*16+16) of every 128-row half;
    // global source pre-swizzled so read-side XOR with (row&7) sees linear k.
    const int rg = lane >> 3;
    const int kc = (lane & 7) ^ rg;
    const unsigned short* gA = A  + (size_t)(m0 + w0 * 16 + rg) * K + kc * 8;
    const unsigned short* gB = BT + (size_t)(n0 + w0 * 16 + rg) * K + kc * 8;
    const int dst0 = (w0 * 16) * 64 + lane * 8;

    // prologue: tile0 fully, tile1 A0+B0; vmcnt(4) leaves t1's units in flight
    G_U(0, 0, 0, 0); G_U(0, 1, 0, 0); G_U(1, 0, 0, 0); G_U(1, 1, 0, 0);
    G_U(0, 0, 1, 1); G_U(1, 0, 1, 1);
    asm volatile("s_waitcnt vmcnt(4)" ::: "memory");
    G_BAR();

    for (int t = 0; t < NK; ++t) {
        const int cb  = (t & 1) * 16384;
        const int nxt = (t & 1) ^ 1;
        bf16x8 afr[4], bS0[4], bS1[4];

        // ---- ph_a: slice0, m-half0; stage A1 of t+1 ----
#pragma unroll
        for (int j = 0; j < 4; ++j) bS0[j] = LDB(j, 0);
#pragma unroll
        for (int i = 0; i < 4; ++i) afr[i] = LDA(i, 0);
        if (t + 1 < NK) G_U(0, 1, nxt, t + 1);
        G_BAR(); G_LGKM();
        __builtin_amdgcn_s_setprio(1);
        G_MFMA16(0, bS0)
        __builtin_amdgcn_s_setprio(0);
        G_BAR();

        // ---- ph_b: slice0, m-half1; stage B1 of t+1 ----
#pragma unroll
        for (int i = 0; i < 4; ++i) afr[i] = LDA(4 + i, 0);
        if (t + 1 < NK) G_U(1, 1, nxt, t + 1);
        G_BAR(); G_LGKM();
        __builtin_amdgcn_s_setprio(1);
        G_MFMA16(4, bS0)
        __builtin_amdgcn_s_setprio(0);
        G_BAR();

        // ---- ph_c: slice1, m-half0 ----
#pragma unroll
        for (int j = 0; j < 4; ++j) bS1[j] = LDB(j, 1);
#pragma unroll
        for (int i = 0; i < 4; ++i) afr[i] = LDA(i, 1);
        G_BAR(); G_LGKM();
        __builtin_amdgcn_s_setprio(1);
        G_MFMA16(0, bS1)
        __builtin_amdgcn_s_setprio(0);
        G_BAR();

        // ---- ph_d: slice1, m-half1; stage A0,B0 of t+2; counted vmcnt ----
#pragma unroll
        for (int i = 0; i < 4; ++i) afr[i] = LDA(4 + i, 1);
        if (t + 2 < NK) { G_U(0, 0, t & 1, t + 2); G_U(1, 0, t & 1, t + 2); }
        G_BAR(); G_LGKM();
        __builtin_amdgcn_s_setprio(1);
        G_MFMA16(4, bS1)
        __builtin_amdgcn_s_setprio(0);
        if (t + 2 < NK) asm volatile("s_waitcnt vmcnt(4)" ::: "memory");
        else            asm volatile("s_waitcnt vmcnt(0)" ::: "memory");
        G_BAR();
    }

    // ---- epilogue: two 128-row halves through LDS (stride 280 shorts) ----
    float bv[4];
#pragma unroll
    for (int j = 0; j < 4; ++j) {
        const int col = n0 + wc * 64 + j * 16 + ml;
        bv[j] = (col < bias_n) ? bias[col] : 0.f;
    }
    for (int h = 0; h < 2; ++h) {
        if (wr == h) {
#pragma unroll
            for (int i = 0; i < 8; ++i)
#pragma unroll
                for (int j = 0; j < 4; ++j)
#pragma unroll
                    for (int r = 0; r < 4; ++r) {
                        float v = acc[i][j][r] + bv[j];
                        if (relu) v = fmaxf(v, 0.f);
                        lds[(i * 16 + q * 4 + r) * 280 + wc * 64 + j * 16 + ml] = f2bf(v);
                    }
        }
        __syncthreads();
#pragma unroll
        for (int p = 0; p < 8; ++p) {
            const int row  = p * 16 + (tid >> 5);
            const int c8   = (tid & 31) * 8;
            const int grow = m0 + h * 128 + row;
            if (grow < MPAD) {
                *(uint4*)&C[(size_t)grow * N + n0 + c8] =
                    *(const uint4*)&lds[row * 280 + c8];
            }
        }
        __syncthreads();
    }
}

// ---------------- k_prep: A1 gather-activate | W2T | W3T | slots ----------
__global__ __launch_bounds__(256)
void k_prep(const float* __restrict__ W1, const float* __restrict__ b1,
            const int* __restrict__ flags, const int* __restrict__ remap,
            unsigned short* __restrict__ A1,
            const float* __restrict__ W2, unsigned short* __restrict__ W2T,
            const float* __restrict__ W3, unsigned short* __restrict__ W3T,
            const int* __restrict__ ingrs, const int* __restrict__ lengths,
            int* __restrict__ slots)
{
    __shared__ float t[64][65];
    const int bid = blockIdx.x;
    const int tid = threadIdx.x;

    if (bid < 15000) {                       // 2 vocab rows per block
        const int id = bid * 2 + (tid >> 7);
        if (flags[id] != 1) return;
        const int row = remap[id];
        const int k4  = (tid & 127) * 4;
        const float4 w  = *(const float4*)(W1 + (size_t)id * 512 + k4);
        const float4 bb = *(const float4*)(b1 + k4);
        unsigned short o[4];
        o[0] = f2bf(fmaxf(w.x + bb.x, 0.f));
        o[1] = f2bf(fmaxf(w.y + bb.y, 0.f));
        o[2] = f2bf(fmaxf(w.z + bb.z, 0.f));
        o[3] = f2bf(fmaxf(w.w + bb.w, 0.f));
        *(uint2*)(A1 + (size_t)row * 512 + k4) = *(const uint2*)o;
    } else if (bid < 15128) {                // W2 [512x1024] -> W2T [1024x512]
        const int local = bid - 15000;
        transpose_body(W2, W2T, 512, 1024, (local & 15) * 64, (local >> 4) * 64, tid, t);
    } else if (bid < 15640) {                // W3 [1024x2047] -> W3T [2048x1024]
        const int local = bid - 15128;
        transpose_body(W3, W3T, 1024, 2047, (local & 31) * 64, (local >> 5) * 64, tid, t);
    } else {                                 // slots[b,l] = remap[ingrs[b,l]]
        const int i = (bid - 15640) * 256 + tid;
        if (i < 4096 * 20) {
            const int b = i / 20;
            const int l = i - b * 20;
            if (l < lengths[b]) slots[i] = remap[ingrs[i]];
        }
    }
}

// ---------------- GEMM kernels (unified body) ----------------
__global__ __launch_bounds__(512, 2)
void k_gemm1(const unsigned short* __restrict__ A1, const unsigned short* __restrict__ W2T,
             const float* __restrict__ b2, unsigned short* __restrict__ H2,
             const int* __restrict__ cnt)
{
    __shared__ __align__(16) unsigned short lds[65536];
    const int mc = (*cnt + 255) & ~255;
    gemm256_body(lds, A1, W2T, b2, 1024, H2, 512, 8, 1024, 1, mc, blockIdx.x, 2);
}

__global__ __launch_bounds__(512, 2)
void k_gemm2(const unsigned short* __restrict__ H2, const unsigned short* __restrict__ W3T,
             const float* __restrict__ b3, unsigned short* __restrict__ Table,
             const int* __restrict__ cnt)
{
    __shared__ __align__(16) unsigned short lds[65536];
    const int mc = (*cnt + 255) & ~255;
    gemm256_body(lds, H2, W3T, b3, 2047, Table, 1024, 16, 2048, 0, mc, blockIdx.x, 3);
}

// ---------------- k_gather: one wave per batch row, 3-deep prefetch -------
__global__ __launch_bounds__(64)
void k_gather(const int* __restrict__ lengths, const int* __restrict__ slots,
              const unsigned short* __restrict__ Table, float* __restrict__ out)
{
    const int b    = blockIdx.x;
    const int lane = threadIdx.x;

    float acc[32];
#pragma unroll
    for (int j = 0; j < 32; ++j) acc[j] = 0.f;

    const int len = lengths[b];
    if (len > 0) {
        uint4 u0[4], u1[4], u2[4];
        {
            const uint4* rp = (const uint4*)(Table + (size_t)slots[b * 20] * 2048);
#pragma unroll
            for (int c = 0; c < 4; ++c) u0[c] = rp[c * 64 + lane];
        }
        if (len > 1) {
            const uint4* rp = (const uint4*)(Table + (size_t)slots[b * 20 + 1] * 2048);
#pragma unroll
            for (int c = 0; c < 4; ++c) u1[c] = rp[c * 64 + lane];
        }
        if (len > 2) {
            const uint4* rp = (const uint4*)(Table + (size_t)slots[b * 20 + 2] * 2048);
#pragma unroll
            for (int c = 0; c < 4; ++c) u2[c] = rp[c * 64 + lane];
        }
        for (int l = 0; l < len; ++l) {
            uint4 cu[4];
#pragma unroll
            for (int c = 0; c < 4; ++c) { cu[c] = u0[c]; u0[c] = u1[c]; u1[c] = u2[c]; }
            if (l + 3 < len) {                       // 3-deep prefetch
                const uint4* rp = (const uint4*)(Table + (size_t)slots[b * 20 + l + 3] * 2048);
#pragma unroll
                for (int c = 0; c < 4; ++c) u2[c] = rp[c * 64 + lane];
            }
            float v[32];
#pragma unroll
            for (int c = 0; c < 4; ++c) {
                v[c*8+0] = bf2f(cu[c].x & 0xffffu); v[c*8+1] = bf2f(cu[c].x >> 16);
                v[c*8+2] = bf2f(cu[c].y & 0xffffu); v[c*8+3] = bf2f(cu[c].y >> 16);
                v[c*8+4] = bf2f(cu[c].z & 0xffffu); v[c*8+5] = bf2f(cu[c].z >> 16);
                v[c*8+6] = bf2f(cu[c].w & 0xffffu); v[c*8+7] = bf2f(cu[c].w >> 16);
            }
            float s = 0.f;
#pragma unroll
            for (int j = 0; j < 32; ++j) s += v[j] * v[j];
#pragma unroll
            for (int off = 1; off < 64; off <<= 1) s += __shfl_xor(s, off, 64);
            const float invn = 1.0f / fmaxf(sqrtf(s), 1e-12f);
#pragma unroll
            for (int j = 0; j < 32; ++j) acc[j] += v[j] * invn;
        }
    }

    const size_t base = (size_t)b * 2047;
#pragma unroll
    for (int c = 0; c < 4; ++c) {
        const int col = (c * 64 + lane) * 8;
        if (c < 3 || lane != 63) {               // full 8 floats in-range
            *(float4*)&out[base + col]     = *(const float4*)&acc[c * 8];
            *(float4*)&out[base + col + 4] = *(const float4*)&acc[c * 8 + 4];
        } else {
#pragma unroll
            for (int j = 0; j < 7; ++j) out[base + col + j] = acc[c * 8 + j];
        }
    }
}

// ---------------- launch ----------------

extern "C" void kernel_launch(void* const* d_in, const int* in_sizes, int n_in,
                              void* d_out, int out_size, void* d_ws, size_t ws_size,
                              hipStream_t stream)
{
    const int*   ingrs   = (const int*)d_in[0];
    const int*   lengths = (const int*)d_in[1];
    const float* W1 = (const float*)d_in[2];
    const float* b1 = (const float*)d_in[3];
    const float* W2 = (const float*)d_in[4];
    const float* b2 = (const float*)d_in[5];
    const float* W3 = (const float*)d_in[6];
    const float* b3 = (const float*)d_in[7];
    float* out = (float*)d_out;

    char* ws = (char*)d_ws;
    unsigned short* A1    = (unsigned short*)(ws);
    unsigned short* H2    = (unsigned short*)(ws + 30801920);
    unsigned short* Table = (unsigned short*)(ws + 92405760);
    unsigned short* W2T   = (unsigned short*)(ws + 215613440);
    unsigned short* W3T   = (unsigned short*)(ws + 216662016);
    int*            flags = (int*)(ws + 220856320);
    int*            remap = (int*)(ws + 220976320);
    int*            cnt   = (int*)(ws + 221096320);
    int*            slots = (int*)(ws + 221216448);

    k_mark  <<<(4096 * 20 + 255) / 256, 256, 0, stream>>>(ingrs, lengths, flags, cnt);
    k_assign<<<(VOCAB + 255) / 256, 256, 0, stream>>>(flags, remap, cnt);
    // a1c (15000) | W2T (128) | W3T (512) | slots (320)
    k_prep<<<15960, 256, 0, stream>>>(W1, b1, flags, remap, A1, W2, W2T,
                                      W3, W3T, ingrs, lengths, slots);
    // GEMM1 (256^2 4-phase): H2 = relu(A1 @ W2 + b2)
    k_gemm1<<<G_MT * 4, 512, 0, stream>>>(A1, W2T, b2, H2, cnt);
    // GEMM2 (256^2 4-phase): Table = H2 @ W3 + b3
    k_gemm2<<<G_MT * 8, 512, 0, stream>>>(H2, W3T, b3, Table, cnt);

    k_gather<<<4096, 64, 0, stream>>>(lengths, slots, Table, out);
}